// Round 14
// baseline (830.269 us; speedup 1.0000x reference)
//
#include <hip/hip_runtime.h>

// EquiConv fused MFMA kernel for MI355X (gfx950) — round 16: M-split + LDS-shared
// weights. Machine model pinned by R7-R15: total = chunk-visits x T_chunk /
// wave-slots; T_chunk = 3.1Kcy/6KB chunk = ~2 B/cy PER-WAVE vmem rate
// (invariant to depth/fences/buffering; per-block time residency-independent).
// Register-resident T=4 spilled 3x -> traffic must drop WITHOUT more regs/wave.
// R16: 512-thread blocks (8 waves), 256 edges/block, each wave = R12's exact
// per-wave shape (T=2, 96 acc f32, proven no-spill) sweeping FULL K (208
// chunks) from LDS-staged chunks: each chunk loaded ONCE per block via
// global_load_lds (4-chunk groups, 2-deep ring 48KB, 1 barrier/group).
// Traffic 780 -> 99 MB; weights L2-resident. NO cross-wave reduce (each
// wave's K complete); all 8 waves run FC+epilogue on own subtiles.
// 79 blocks <= 256 CUs -> single round. LDS 130KB -> 1 blk/CU (2 waves/SIMD).
// Group-order rotated by blockIdx%52 for skew. prep_weights unchanged (R7).

#define E_TOT 20000
#define EPB   256
#define NBLK  79               // ceil(20000/256); last block 32 edges

typedef __attribute__((ext_vector_type(8))) short short8;
typedef __attribute__((ext_vector_type(4))) float f32x4;
typedef __attribute__((ext_vector_type(2))) __bf16 bf16x2;

#define FRAG_USH 512
#define CH_USH   3072          // 6 frags = 6KB
#define STRIDE_W 159744        // per-K-segment stream (ushorts)
#define FC1_OFF  638976
#define FC2_OFF  647168
#define FC3_OFF  651264
#define WS_USH   657408

#define GRP_USH  12288         // 4 chunks
#define NGRP     52            // 4 segments x 13 groups

// LDS pool (bytes): ring 49152 | x1s 256x66x2=33792 | x1v 256x98x2=50176
#define X1S_OFF  49152
#define X1V_OFF  82944
#define POOL_B   133120        // 130 KB -> 1 block/CU

__device__ __forceinline__ unsigned short f2b(float f){
  return __builtin_bit_cast(unsigned short, (__bf16)f);
}
__device__ __forceinline__ unsigned f2b2(float lo, float hi){
  bf16x2 t; t[0] = (__bf16)lo; t[1] = (__bf16)hi;
  return __builtin_bit_cast(unsigned, t);
}
__device__ __forceinline__ float b2f(unsigned short h){
  return __uint_as_float(((unsigned)h) << 16);
}
__device__ __forceinline__ float ulo(unsigned u){ return __uint_as_float(u << 16); }
__device__ __forceinline__ float uhi(unsigned u){ return __uint_as_float(u & 0xFFFF0000u); }
__device__ __forceinline__ f32x4 mfma16(short8 a, short8 b, f32x4 c){
  return __builtin_amdgcn_mfma_f32_16x16x32_bf16(a, b, c, 0, 0, 0);
}
union U8 { short8 v; unsigned u[4]; };
__device__ __forceinline__ float silu_f(float x){ return x/(1.f+__expf(-x)); }
__device__ __forceinline__ float sigm_f(float x){ return 1.f/(1.f+__expf(-x)); }

#define PACK8P(a, s, xp) { \
  a.u[0]=f2b2((s)*ulo((xp)[0]),(s)*uhi((xp)[0])); \
  a.u[1]=f2b2((s)*ulo((xp)[1]),(s)*uhi((xp)[1])); \
  a.u[2]=f2b2((s)*ulo((xp)[2]),(s)*uhi((xp)[2])); \
  a.u[3]=f2b2((s)*ulo((xp)[3]),(s)*uhi((xp)[3])); }

__device__ __forceinline__ int fpos(int kl, int n16){
  return (kl>>3)*128 + n16*8 + (kl&7);
}

// ---------------- prep: dest-linear gather (unchanged from R7) ----------------
__global__ void prep_weights(const float* __restrict__ ss_s, const float* __restrict__ ss_g,
                             const float* __restrict__ vv_s, const float* __restrict__ vv_g,
                             const float* __restrict__ sv,   const float* __restrict__ vs,
                             const float* __restrict__ w1,   const float* __restrict__ w2,
                             const float* __restrict__ w3,   unsigned short* __restrict__ wsb)
{
  int g = blockIdx.x * 256 + threadIdx.x;
  if (g >= WS_USH/8) return;
  const int dest = g << 3;
  const float A_SC  = 0.013975424859373686f;
  const float A_VV  = (float)(0.013975424859373686 * 0.5773502691896258);
  const float A_VEC = 0.015625f;

  const float* src = nullptr;
  int stride = 0;
  float scale = 1.f;

  if (dest < FC1_OFF) {
    int wave = dest / STRIDE_W;
    int off  = dest - wave*STRIDE_W;
    int c    = off / CH_USH;
    int rem  = off - c*CH_USH;
    int t    = rem >> 9;
    int p    = rem & 511;
    int kl   = (p >> 7) << 3;
    int n16  = (p >> 3) & 15;
    if (c < 32) {
      int u = (wave<<4) + (c>>1);
      int v = ((c&1)<<5) + kl;
      if (t < 4) { src = ss_s + (u<<12)+(v<<6)+((t<<4)+n16);     stride = 64; }
      else       { src = ss_g + (u<<11)+(v<<5)+(((t-4)<<4)+n16); stride = 32; }
      scale = A_SC;
    } else if (c < 40) {
      int u = (wave<<3) + (c-32);
      int v = kl;
      if (t < 4) { src = vv_s + (u<<11)+(v<<6)+((t<<4)+n16);     stride = 64; }
      else       { src = vv_g + (u<<10)+(v<<5)+(((t-4)<<4)+n16); stride = 32; }
      scale = A_VV;
    } else if (c < 46) {
      int ul = (c-40)*3 + (t>>1);
      if (ul < 16) {
        int u = (wave<<4) + ul;
        src = sv + (u<<10)+(kl<<5)+(((t&1)<<4)+n16);
        stride = 32; scale = A_VEC;
      }
    } else {
      int cc = c - 46;
      int vh = cc/3, ch3 = cc - vh*3;
      int fseq = ch3*6 + t;
      if (fseq < 16) {
        int u = (wave<<3) + (fseq>>1);
        int v = (vh<<5) + kl;
        src = vs + (u<<11)+(v<<5)+(((fseq&1)<<4)+n16);
        stride = 32; scale = A_VEC;
      }
    }
  } else if (dest < FC2_OFF) {
    int off = dest - FC1_OFF;
    int fi = off >> 9, p = off & 511;
    int kl = (p>>7)<<3, n16 = (p>>3)&15;
    int k = ((fi>>2)<<5) + kl, n = ((fi&3)<<4) + n16;
    src = w1 + (k<<6) + n; stride = 64;
  } else if (dest < FC3_OFF) {
    int off = dest - FC2_OFF;
    int fi = off >> 9, p = off & 511;
    int kl = (p>>7)<<3, n16 = (p>>3)&15;
    int k = ((fi>>2)<<5) + kl, n = ((fi&3)<<4) + n16;
    src = w2 + (k<<6) + n; stride = 64;
  } else {
    int off = dest - FC3_OFF;
    int fi = off >> 9, p = off & 511;
    int kl = (p>>7)<<3, n16 = (p>>3)&15;
    int koff = fi/6, nhi = fi - koff*6;
    int k = (koff<<5) + kl, n = (nhi<<4) + n16;
    src = w3 + k*96 + n; stride = 96;
  }

  U8 a;
  if (src) {
    float v0 = scale * src[0*stride], v1 = scale * src[1*stride];
    float v2 = scale * src[2*stride], v3 = scale * src[3*stride];
    float v4 = scale * src[4*stride], v5 = scale * src[5*stride];
    float v6 = scale * src[6*stride], v7 = scale * src[7*stride];
    a.u[0] = f2b2(v0, v1); a.u[1] = f2b2(v2, v3);
    a.u[2] = f2b2(v4, v5); a.u[3] = f2b2(v6, v7);
  } else {
    a.u[0] = 0; a.u[1] = 0; a.u[2] = 0; a.u[3] = 0;
  }
  *(short8*)(wsb + dest) = a.v;
}

// ---------------- main fused kernel ----------------
__global__ __launch_bounds__(512, 2)
void equiconv_main(const float* __restrict__ fea1,
                   const float* __restrict__ fea2,
                   const float* __restrict__ few,
                   const float* __restrict__ fb1,
                   const float* __restrict__ fb2,
                   const float* __restrict__ fb3,
                   const unsigned short* __restrict__ wsb,
                   float* __restrict__ out)
{
  __shared__ __align__(16) unsigned char pool[POOL_B];
  unsigned short* rbuf = (unsigned short*)pool;                 // 49152 B ring
  unsigned short* x1s_ = (unsigned short*)(pool + X1S_OFF);     // [256][66]
  unsigned short* x1v_ = (unsigned short*)(pool + X1V_OFF);     // [256][98]
  unsigned short* hb_  = (unsigned short*)pool;                 // alias ring (dead post-K)

  #define X1S(r, cc) x1s_[(r)*66 + (cc)]
  #define X1V(r, cc) x1v_[(r)*98 + (cc)]
  #define HB(w, r, cc) hb_[(((w)<<4) + (r))*72 + (cc)]

  const int tid  = threadIdx.x;
  const int lane = tid & 63, wv = tid >> 6;   // 8 waves
  const int ln   = lane & 15, quad = lane >> 4, q8 = quad << 3;
  const int ebase = blockIdx.x << 8;          // 256 edges/block
  const int offg  = blockIdx.x % NGRP;

  // ---- stage x1 (256 edges) into LDS as bf16; clamp last-block rows ----
  for (int it = tid; it < 10240; it += 512){
    int row = it / 40, seg = it - row*40;
    int er = ebase + row; if (er > E_TOT-1) er = E_TOT-1;
    float4 v1 = *(const float4*)(fea1 + (size_t)er*160 + seg*4);
    const float* p1 = (const float*)&v1;
    int c0 = seg*4;
    #pragma unroll
    for (int jj = 0; jj < 4; jj++){
      int col = c0 + jj;
      if (col < 64) X1S(row, col) = f2b(p1[jj]);
      else          X1V(row, col-64) = f2b(p1[jj]);
    }
  }

  // ---- per-wave x2 hoist, packed bf16 pairs (40 VGPRs); clamp rows ----
  unsigned xep[2][4], xop[2][4], y0p[2][4], y1p[2][4], y2p[2][4];
  #pragma unroll
  for (int s = 0; s < 2; s++){
    int er = ebase + (wv<<5) + s*16 + ln; if (er > E_TOT-1) er = E_TOT-1;
    const float* p = fea2 + (size_t)er*160;
    float4 a0 = *(const float4*)(p + q8);
    float4 a1 = *(const float4*)(p + q8 + 4);
    float4 b0 = *(const float4*)(p + 32 + q8);
    float4 b1 = *(const float4*)(p + 36 + q8);
    xep[s][0]=f2b2(a0.x,a0.y); xep[s][1]=f2b2(a0.z,a0.w);
    xep[s][2]=f2b2(a1.x,a1.y); xep[s][3]=f2b2(a1.z,a1.w);
    xop[s][0]=f2b2(b0.x,b0.y); xop[s][1]=f2b2(b0.z,b0.w);
    xop[s][2]=f2b2(b1.x,b1.y); xop[s][3]=f2b2(b1.z,b1.w);
    const float* py = p + 64 + q8*3;
    float yb[24];
    #pragma unroll
    for (int t = 0; t < 12; t++){
      float2 f2v = *(const float2*)(py + 2*t);
      yb[2*t] = f2v.x; yb[2*t+1] = f2v.y;
    }
    #pragma unroll
    for (int q = 0; q < 4; q++){
      y0p[s][q] = f2b2(yb[6*q+0], yb[6*q+3]);
      y1p[s][q] = f2b2(yb[6*q+1], yb[6*q+4]);
      y2p[s][q] = f2b2(yb[6*q+2], yb[6*q+5]);
    }
  }

  // ---- cooperative group staging: 4 chunks (24KB) per group ----
  auto stage = [&](int g, int buf){
    int st = g / 13, gi = g - st*13;
    const unsigned short* sp = wsb + (size_t)st*STRIDE_W + gi*(4*CH_USH) + tid*8;
    unsigned short* dp = rbuf + buf*GRP_USH + (wv<<9);   // wave-uniform dest
    #pragma unroll
    for (int q = 0; q < 3; q++)
      __builtin_amdgcn_global_load_lds(
        (const __attribute__((address_space(1))) unsigned int*)(sp + q*4096),
        (__attribute__((address_space(3))) unsigned int*)(dp + q*4096),
        16, 0, 0);
  };
  stage(offg, 0);

  const int r0 = (wv<<5) + ln, r1 = (wv<<5) + 16 + ln;
  const f32x4 z4 = {0.f,0.f,0.f,0.f};
  f32x4 accS[2][6] = {{z4,z4,z4,z4,z4,z4},{z4,z4,z4,z4,z4,z4}};
  f32x4 accV[2][3][2] = {{{z4,z4},{z4,z4},{z4,z4}},{{z4,z4},{z4,z4},{z4,z4}}};

  // ---- K loop: 52 groups x 4 chunks; every wave consumes every chunk ----
  #pragma unroll 1
  for (int i = 0; i < NGRP; i++){
    __syncthreads();                         // drains vmcnt: buf[i&1] ready; prev reads done
    if (i+1 < NGRP){
      int gn = i + 1 + offg; if (gn >= NGRP) gn -= NGRP;
      stage(gn, (i+1)&1);
    }
    int g = i + offg; if (g >= NGRP) g -= NGRP;
    int st = g / 13, gi = g - st*13, c0 = gi*4;
    const unsigned short* bbase = rbuf + (i&1)*GRP_USH + lane*8;

    #pragma unroll 1
    for (int cc = 0; cc < 4; cc++){
      int c = c0 + cc;
      short8 bb[6];
      #pragma unroll
      for (int t = 0; t < 6; t++)
        bb[t] = *(const short8*)(bbase + cc*CH_USH + t*FRAG_USH);

      if (c < 32) {                          // ===== SS =====
        int u = (st<<4) + (c>>1);
        float s0v = b2f(X1S(r0, u));
        float s1v = b2f(X1S(r1, u));
        U8 a0, a1;
        if (c & 1){ PACK8P(a0, s0v, xop[0]); PACK8P(a1, s1v, xop[1]); }
        else      { PACK8P(a0, s0v, xep[0]); PACK8P(a1, s1v, xep[1]); }
        #pragma unroll
        for (int t = 0; t < 6; t++){
          accS[0][t] = mfma16(a0.v, bb[t], accS[0][t]);
          accS[1][t] = mfma16(a1.v, bb[t], accS[1][t]);
        }
      } else if (c < 40) {                   // ===== VV =====
        int u = (st<<3) + (c - 32);
        U8 a0, a1;
        {
          float c0v = b2f(X1V(r0, u*3+0));
          float c1v = b2f(X1V(r0, u*3+1));
          float c2v = b2f(X1V(r0, u*3+2));
          #pragma unroll
          for (int q = 0; q < 4; q++){
            float lo = c0v*ulo(y0p[0][q]) + c1v*ulo(y1p[0][q]) + c2v*ulo(y2p[0][q]);
            float hi = c0v*uhi(y0p[0][q]) + c1v*uhi(y1p[0][q]) + c2v*uhi(y2p[0][q]);
            a0.u[q] = f2b2(lo, hi);
          }
        }
        {
          float c0v = b2f(X1V(r1, u*3+0));
          float c1v = b2f(X1V(r1, u*3+1));
          float c2v = b2f(X1V(r1, u*3+2));
          #pragma unroll
          for (int q = 0; q < 4; q++){
            float lo = c0v*ulo(y0p[1][q]) + c1v*ulo(y1p[1][q]) + c2v*ulo(y2p[1][q]);
            float hi = c0v*uhi(y0p[1][q]) + c1v*uhi(y1p[1][q]) + c2v*uhi(y2p[1][q]);
            a1.u[q] = f2b2(lo, hi);
          }
        }
        #pragma unroll
        for (int t = 0; t < 6; t++){
          accS[0][t] = mfma16(a0.v, bb[t], accS[0][t]);
          accS[1][t] = mfma16(a1.v, bb[t], accS[1][t]);
        }
      } else if (c < 46) {                   // ===== SV =====
        int ch = c - 40;
        #pragma unroll
        for (int uu = 0; uu < 3; uu++){
          int ui = ch*3 + uu;
          if (ui < 16){
            int u = (st<<4) + ui;
            float s0v = b2f(X1S(r0, u));
            float s1v = b2f(X1S(r1, u));
            U8 a[2][3];
            PACK8P(a[0][0], s0v, y0p[0]); PACK8P(a[0][1], s0v, y1p[0]); PACK8P(a[0][2], s0v, y2p[0]);
            PACK8P(a[1][0], s1v, y0p[1]); PACK8P(a[1][1], s1v, y1p[1]); PACK8P(a[1][2], s1v, y2p[1]);
            #pragma unroll
            for (int t = 0; t < 2; t++){
              short8 b8 = bb[uu*2 + t];
              #pragma unroll
              for (int s = 0; s < 2; s++)
                #pragma unroll
                for (int i2 = 0; i2 < 3; i2++)
                  accV[s][i2][t] = mfma16(a[s][i2].v, b8, accV[s][i2][t]);
            }
          }
        }
      } else {                               // ===== VS =====
        int pc = c - 46;
        int p = (pc >= 3) ? 1 : 0;
        int ch = pc - 3*p;
        #pragma unroll
        for (int uu = 0; uu < 3; uu++){
          int ui = ch*3 + uu;
          if (ui < 8){
            int u = (st<<3) + ui;
            U8 a[2][3];
            #pragma unroll
            for (int s = 0; s < 2; s++){
              int rr = s ? r1 : r0;
              float c0v = b2f(X1V(rr, u*3+0));
              float c1v = b2f(X1V(rr, u*3+1));
              float c2v = b2f(X1V(rr, u*3+2));
              if (p){ PACK8P(a[s][0], c0v, xop[s]); PACK8P(a[s][1], c1v, xop[s]); PACK8P(a[s][2], c2v, xop[s]); }
              else  { PACK8P(a[s][0], c0v, xep[s]); PACK8P(a[s][1], c1v, xep[s]); PACK8P(a[s][2], c2v, xep[s]); }
            }
            #pragma unroll
            for (int t = 0; t < 2; t++){
              short8 b8 = bb[uu*2 + t];
              #pragma unroll
              for (int s = 0; s < 2; s++)
                #pragma unroll
                for (int i2 = 0; i2 < 3; i2++)
                  accV[s][i2][t] = mfma16(a[s][i2].v, b8, accV[s][i2][t]);
            }
          }
        }
      }
    }
  }
  __syncthreads();            // all waves done reading ring/x1 before hb alias

  // ---- FC + epilogue: each wave handles its own 2 subtiles; no reduce ----
  if (ebase + (wv<<5) < E_TOT) {
    #pragma unroll
    for (int s = 0; s < 2; s++){
      f32x4 P[12];
      #pragma unroll
      for (int t = 0; t < 6; t++) P[t] = accS[s][t];
      #pragma unroll
      for (int t = 0; t < 2; t++)
        #pragma unroll
        for (int i2 = 0; i2 < 3; i2++)
          P[6+3*t+i2] = accV[s][i2][t];

      const f32x4 z4b = {0.f,0.f,0.f,0.f};
      f32x4 accF[4] = {z4b,z4b,z4b,z4b};
      {
        const float* fwp = few + (size_t)(ebase + (wv<<5) + s*16 + ln)*128;
        const short8* B = (const short8*)(wsb + FC1_OFF);
        #pragma unroll
        for (int c = 0; c < 4; c++){
          float4 fa  = *(const float4*)(fwp + c*32 + q8);
          float4 fbv = *(const float4*)(fwp + c*32 + q8 + 4);
          U8 a;
          a.u[0]=f2b2(fa.x,fa.y);   a.u[1]=f2b2(fa.z,fa.w);
          a.u[2]=f2b2(fbv.x,fbv.y); a.u[3]=f2b2(fbv.z,fbv.w);
          #pragma unroll
          for (int t = 0; t < 4; t++) accF[t] = mfma16(a.v, B[(c*4+t)*64 + lane], accF[t]);
        }
      }
      #pragma unroll
      for (int t = 0; t < 4; t++){
        float bbv = fb1[(t<<4)+ln];
        #pragma unroll
        for (int r = 0; r < 4; r++)
          HB(wv, (quad<<2)+r, (t<<4)+ln) = f2b(silu_f(accF[t][r] + bbv));
      }
      f32x4 acc2[4] = {z4b,z4b,z4b,z4b};
      {
        const short8* B = (const short8*)(wsb + FC2_OFF);
        #pragma unroll
        for (int c = 0; c < 2; c++){
          uint4 hq = *(const uint4*)&HB(wv, ln, c*32 + q8);
          U8 a; a.u[0]=hq.x; a.u[1]=hq.y; a.u[2]=hq.z; a.u[3]=hq.w;
          #pragma unroll
          for (int t = 0; t < 4; t++) acc2[t] = mfma16(a.v, B[(c*4+t)*64 + lane], acc2[t]);
        }
      }
      #pragma unroll
      for (int t = 0; t < 4; t++){
        float bbv = fb2[(t<<4)+ln];
        #pragma unroll
        for (int r = 0; r < 4; r++)
          HB(wv, (quad<<2)+r, (t<<4)+ln) = f2b(silu_f(acc2[t][r] + bbv));
      }
      f32x4 acc3[6] = {z4b,z4b,z4b,z4b,z4b,z4b};
      {
        const short8* B = (const short8*)(wsb + FC3_OFF);
        #pragma unroll
        for (int c = 0; c < 2; c++){
          uint4 hq = *(const uint4*)&HB(wv, ln, c*32 + q8);
          U8 a; a.u[0]=hq.x; a.u[1]=hq.y; a.u[2]=hq.z; a.u[3]=hq.w;
          #pragma unroll
          for (int t = 0; t < 6; t++) acc3[t] = mfma16(a.v, B[(c*6+t)*64 + lane], acc3[t]);
        }
      }

      #pragma unroll
      for (int r = 0; r < 4; r++){
        int eg = ebase + (wv<<5) + s*16 + (quad<<2) + r;
        float* op = out + (size_t)eg*160;
        #pragma unroll
        for (int t = 0; t < 4; t++)
          op[(t<<4)+ln] = silu_f(P[t][r]) * (acc3[t][r] + fb3[(t<<4)+ln]);
        #pragma unroll
        for (int tp = 0; tp < 2; tp++){
          int wc = (tp<<4) + ln;
          float f = sigm_f(P[4+tp][r]) * (acc3[4+tp][r] + fb3[64+wc]);
          op[64 + wc*3 + 0] = P[6+3*tp+0][r] * f;
          op[64 + wc*3 + 1] = P[6+3*tp+1][r] * f;
          op[64 + wc*3 + 2] = P[6+3*tp+2][r] * f;
        }
      }
    }
  }
}

extern "C" void kernel_launch(void* const* d_in, const int* in_sizes, int n_in,
                              void* d_out, int out_size, void* d_ws, size_t ws_size,
                              hipStream_t stream) {
  (void)in_sizes; (void)n_in; (void)out_size; (void)ws_size;
  unsigned short* wsb = (unsigned short*)d_ws;

  prep_weights<<<(WS_USH/8 + 255)/256, 256, 0, stream>>>(
      (const float*)d_in[3], (const float*)d_in[5],     // ss_s, ss_g
      (const float*)d_in[4], (const float*)d_in[6],     // vv_s, vv_g
      (const float*)d_in[7], (const float*)d_in[8],     // sv, vs
      (const float*)d_in[9], (const float*)d_in[11], (const float*)d_in[13],
      wsb);

  equiconv_main<<<NBLK, 512, 0, stream>>>(
      (const float*)d_in[0], (const float*)d_in[1], (const float*)d_in[2],
      (const float*)d_in[10], (const float*)d_in[12], (const float*)d_in[14],
      (const unsigned short*)wsb, (float*)d_out);
}

// Round 15
// 173.498 us; speedup vs baseline: 4.7855x; 4.7855x over previous
//
#include <hip/hip_runtime.h>

// EquiConv fused MFMA kernel for MI355X (gfx950) — round 17: REVERT to R12,
// the session's verified best (172.2us total / 82.5us main, measured round 9).
// R16 post-mortem: M-split with 79 blocks at 1 blk/CU idled 69% of CUs
// (Occupancy 7.4% = 632/8192 waves) and barrier-serialized staging -> 750us.
// Elimination series complete: total = 130K chunk-visits x 3.1Kcy / 2048
// wave-slots ~= 82us (matches R12 exactly). Probed and falsified: wait
// granularity/depth/buffering (R8/R9/R11 null), >2 waves/SIMD (R10/R13/R15
// spill, 3 strikes), register T=4 (spill), LDS-shared T=8 (R16 geometry).
// Kept win: per-block staggered chunk order (R12, -11%: spreads 512 resident
// blocks across the 104 half-chunks of the shared 1.28MB stream).
// Remaining unprobed lever: fp8 weights (half traffic) — numerically risky
// vs the absmax budget; not attempted. prep_weights = R7 dest-linear gather.

#define E_TOT 20000

typedef __attribute__((ext_vector_type(8))) short short8;
typedef __attribute__((ext_vector_type(4))) float f32x4;
typedef __attribute__((ext_vector_type(2))) __bf16 bf16x2;

#define FRAG_USH 512
#define CH_USH   3072          // 6 frags = 6KB (stream layout unit)
#define N_CH     52
#define STRIDE_W 159744        // 312 frags * 512 ushort per wave stream
#define FC1_OFF  638976        // 4*STRIDE_W
#define FC2_OFF  647168
#define FC3_OFF  651264
#define WS_USH   657408        // 1.28 MB of d_ws

// LDS pool carve (bytes): redf 30720 | x1s 4224 | x1v 6272 ; hb aliases x1
#define X1S_OFF  30720
#define X1V_OFF  34944
#define POOL_B   41216

__device__ __forceinline__ unsigned short f2b(float f){
  return __builtin_bit_cast(unsigned short, (__bf16)f);
}
__device__ __forceinline__ unsigned f2b2(float lo, float hi){
  bf16x2 t; t[0] = (__bf16)lo; t[1] = (__bf16)hi;
  return __builtin_bit_cast(unsigned, t);
}
__device__ __forceinline__ float b2f(unsigned short h){
  return __uint_as_float(((unsigned)h) << 16);
}
__device__ __forceinline__ float ulo(unsigned u){ return __uint_as_float(u << 16); }
__device__ __forceinline__ float uhi(unsigned u){ return __uint_as_float(u & 0xFFFF0000u); }
__device__ __forceinline__ f32x4 mfma16(short8 a, short8 b, f32x4 c){
  return __builtin_amdgcn_mfma_f32_16x16x32_bf16(a, b, c, 0, 0, 0);
}
union U8 { short8 v; unsigned u[4]; };
__device__ __forceinline__ float silu_f(float x){ return x/(1.f+__expf(-x)); }
__device__ __forceinline__ float sigm_f(float x){ return 1.f/(1.f+__expf(-x)); }

// PACK8P: a = bf16(s * unpack(xp[0..3])), pair order (lo,hi) == (x[2q],x[2q+1])
#define PACK8P(a, s, xp) { \
  a.u[0]=f2b2((s)*ulo((xp)[0]),(s)*uhi((xp)[0])); \
  a.u[1]=f2b2((s)*ulo((xp)[1]),(s)*uhi((xp)[1])); \
  a.u[2]=f2b2((s)*ulo((xp)[2]),(s)*uhi((xp)[2])); \
  a.u[3]=f2b2((s)*ulo((xp)[3]),(s)*uhi((xp)[3])); }

// dest position of (k_local, n16) inside a 512-ushort fragment
__device__ __forceinline__ int fpos(int kl, int n16){
  return (kl>>3)*128 + n16*8 + (kl&7);
}

// ---------------- prep: dest-linear gather into per-wave streams ----------------
__global__ void prep_weights(const float* __restrict__ ss_s, const float* __restrict__ ss_g,
                             const float* __restrict__ vv_s, const float* __restrict__ vv_g,
                             const float* __restrict__ sv,   const float* __restrict__ vs,
                             const float* __restrict__ w1,   const float* __restrict__ w2,
                             const float* __restrict__ w3,   unsigned short* __restrict__ wsb)
{
  int g = blockIdx.x * 256 + threadIdx.x;
  if (g >= WS_USH/8) return;
  const int dest = g << 3;
  const float A_SC  = 0.013975424859373686f;                     // 1/sqrt(S*S+V*V)
  const float A_VV  = (float)(0.013975424859373686 * 0.5773502691896258);
  const float A_VEC = 0.015625f;                                 // 1/sqrt(2*S*V)

  const float* src = nullptr;
  int stride = 0;
  float scale = 1.f;

  if (dest < FC1_OFF) {                      // 4 per-wave streams
    int wave = dest / STRIDE_W;
    int off  = dest - wave*STRIDE_W;
    int c    = off / CH_USH;
    int rem  = off - c*CH_USH;
    int t    = rem >> 9;                     // fragment 0..5
    int p    = rem & 511;
    int kl   = (p >> 7) << 3;                // base kl; +j inside group
    int n16  = (p >> 3) & 15;
    if (c < 32) {                            // SS: ss_s (t0..3) + ss_g (t4,5)
      int u = (wave<<4) + (c>>1);
      int v = ((c&1)<<5) + kl;
      if (t < 4) { src = ss_s + (u<<12)+(v<<6)+((t<<4)+n16);     stride = 64; }
      else       { src = ss_g + (u<<11)+(v<<5)+(((t-4)<<4)+n16); stride = 32; }
      scale = A_SC;
    } else if (c < 40) {                     // VV: vv_s (t0..3) + vv_g (t4,5)
      int u = (wave<<3) + (c-32);
      int v = kl;
      if (t < 4) { src = vv_s + (u<<11)+(v<<6)+((t<<4)+n16);     stride = 64; }
      else       { src = vv_g + (u<<10)+(v<<5)+(((t-4)<<4)+n16); stride = 32; }
      scale = A_VV;
    } else if (c < 46) {                     // SV: chunks 40..45, ul = ch*3 + t/2
      int ul = (c-40)*3 + (t>>1);
      if (ul < 16) {
        int u = (wave<<4) + ul;
        src = sv + (u<<10)+(kl<<5)+(((t&1)<<4)+n16);
        stride = 32; scale = A_VEC;
      }                                      // else: gap frag (c=45,t>=2) -> 0
    } else {                                 // VS: chunks 46..51
      int cc = c - 46;
      int vh = cc/3, ch3 = cc - vh*3;
      int fseq = ch3*6 + t;
      if (fseq < 16) {
        int u = (wave<<3) + (fseq>>1);
        int v = (vh<<5) + kl;
        src = vs + (u<<11)+(v<<5)+(((fseq&1)<<4)+n16);
        stride = 32; scale = A_VEC;
      }                                      // else: gap frag (ch3=2,t>=4) -> 0
    }
  } else if (dest < FC2_OFF) {               // fc1 [128][64]
    int off = dest - FC1_OFF;
    int fi = off >> 9, p = off & 511;
    int kl = (p>>7)<<3, n16 = (p>>3)&15;
    int k = ((fi>>2)<<5) + kl, n = ((fi&3)<<4) + n16;
    src = w1 + (k<<6) + n; stride = 64;
  } else if (dest < FC3_OFF) {               // fc2 [64][64]
    int off = dest - FC2_OFF;
    int fi = off >> 9, p = off & 511;
    int kl = (p>>7)<<3, n16 = (p>>3)&15;
    int k = ((fi>>2)<<5) + kl, n = ((fi&3)<<4) + n16;
    src = w2 + (k<<6) + n; stride = 64;
  } else {                                   // fc3 [64][96]
    int off = dest - FC3_OFF;
    int fi = off >> 9, p = off & 511;
    int kl = (p>>7)<<3, n16 = (p>>3)&15;
    int koff = fi/6, nhi = fi - koff*6;
    int k = (koff<<5) + kl, n = (nhi<<4) + n16;
    src = w3 + k*96 + n; stride = 96;
  }

  U8 a;
  if (src) {
    float v0 = scale * src[0*stride], v1 = scale * src[1*stride];
    float v2 = scale * src[2*stride], v3 = scale * src[3*stride];
    float v4 = scale * src[4*stride], v5 = scale * src[5*stride];
    float v6 = scale * src[6*stride], v7 = scale * src[7*stride];
    a.u[0] = f2b2(v0, v1); a.u[1] = f2b2(v2, v3);
    a.u[2] = f2b2(v4, v5); a.u[3] = f2b2(v6, v7);
  } else {
    a.u[0] = 0; a.u[1] = 0; a.u[2] = 0; a.u[3] = 0;
  }
  *(short8*)(wsb + dest) = a.v;
}

// ---------------- main fused kernel ----------------
__global__ __launch_bounds__(256, 2)
void equiconv_main(const float* __restrict__ fea1,
                   const float* __restrict__ fea2,
                   const float* __restrict__ few,
                   const float* __restrict__ fb1,
                   const float* __restrict__ fb2,
                   const float* __restrict__ fb3,
                   const unsigned short* __restrict__ wsb,
                   float* __restrict__ out)
{
  __shared__ __align__(16) unsigned char pool[POOL_B];
  float*          redf = (float*)pool;                          // [0, 30720)
  unsigned short* x1s_ = (unsigned short*)(pool + X1S_OFF);     // 32*66*2
  unsigned short* x1v_ = (unsigned short*)(pool + X1V_OFF);     // 32*98*2
  unsigned short* hb_  = (unsigned short*)(pool + X1S_OFF);     // alias x1 (dead post-K)

  #define X1S(r, cc) x1s_[(r)*66 + (cc)]
  #define X1V(r, cc) x1v_[(r)*98 + (cc)]
  #define HB(w, r, cc) hb_[(((w)<<4) + (r))*72 + (cc)]

  const int tid  = threadIdx.x;
  const int lane = tid & 63, wv = tid >> 6;
  const int ln   = lane & 15, quad = lane >> 4, q8 = quad << 3;
  const int ebase = blockIdx.x << 5;          // 625 * 32 == 20000 exactly

  // per-block chunk-order stagger (L2 channel spread); block-uniform
  const int off16 = blockIdx.x & 15;
  const int off8  = blockIdx.x & 7;
  const int off6  = blockIdx.x % 6;

  // ---- stage x1 (32 edges) into LDS as bf16 ----
  for (int it = tid; it < 1280; it += 256){
    int row = it / 40, seg = it - row*40;
    float4 v1 = *(const float4*)(fea1 + (size_t)(ebase + row)*160 + seg*4);
    const float* p1 = (const float*)&v1;
    int c0 = seg*4;
    #pragma unroll
    for (int jj = 0; jj < 4; jj++){
      int col = c0 + jj;
      if (col < 64) X1S(row, col) = f2b(p1[jj]);
      else          X1V(row, col-64) = f2b(p1[jj]);
    }
  }
  __syncthreads();

  // ---- hoist per-lane x2 fragments, packed as bf16 pairs (40 VGPRs) ----
  unsigned xep[2][4], xop[2][4], y0p[2][4], y1p[2][4], y2p[2][4];
  #pragma unroll
  for (int s = 0; s < 2; s++){
    const float* p = fea2 + (size_t)(ebase + s*16 + ln)*160;
    float4 a0 = *(const float4*)(p + q8);
    float4 a1 = *(const float4*)(p + q8 + 4);
    float4 b0 = *(const float4*)(p + 32 + q8);
    float4 b1 = *(const float4*)(p + 36 + q8);
    xep[s][0]=f2b2(a0.x,a0.y); xep[s][1]=f2b2(a0.z,a0.w);
    xep[s][2]=f2b2(a1.x,a1.y); xep[s][3]=f2b2(a1.z,a1.w);
    xop[s][0]=f2b2(b0.x,b0.y); xop[s][1]=f2b2(b0.z,b0.w);
    xop[s][2]=f2b2(b1.x,b1.y); xop[s][3]=f2b2(b1.z,b1.w);
    const float* py = p + 64 + q8*3;
    float yb[24];
    #pragma unroll
    for (int t = 0; t < 12; t++){
      float2 f2v = *(const float2*)(py + 2*t);
      yb[2*t] = f2v.x; yb[2*t+1] = f2v.y;
    }
    #pragma unroll
    for (int q = 0; q < 4; q++){
      y0p[s][q] = f2b2(yb[6*q+0], yb[6*q+3]);
      y1p[s][q] = f2b2(yb[6*q+1], yb[6*q+4]);
      y2p[s][q] = f2b2(yb[6*q+2], yb[6*q+5]);
    }
  }

  // ---- register double-buffered B-fragment stream (runtime chunk indices) ----
  const unsigned short* gstream = wsb + (size_t)wv*STRIDE_W + lane*8;
  auto LD = [&](int c, short8* buf){
    const unsigned short* g = gstream + c*CH_USH;
    #pragma unroll
    for (int t = 0; t < 6; t++) buf[t] = *(const short8*)(g + t*FRAG_USH);
  };

  const int r0 = ln, r1 = 16 + ln;            // x1 rows for sub0/sub1
  const f32x4 z4 = {0.f,0.f,0.f,0.f};
  f32x4 accS[2][6] = {{z4,z4,z4,z4,z4,z4},{z4,z4,z4,z4,z4,z4}};
  f32x4 accV[2][3][2] = {{{z4,z4},{z4,z4},{z4,z4}},{{z4,z4},{z4,z4},{z4,z4}}};

  short8 bA[6], bB[6];
  LD(2*off16, bA);                            // first visited SS pair, even chunk

  // ===== SS: pairs rotated by off16; pair p -> chunks 2p (xe), 2p+1 (xo) =====
  #pragma unroll 1
  for (int i = 0; i < 16; i++){
    int p  = (i + off16) & 15;
    int pn = (i + 1 + off16) & 15;
    int u = (wv<<4) + p;
    float s0 = b2f(X1S(r0, u));
    float s1 = b2f(X1S(r1, u));
    {                                        // even chunk 2p from bA
      LD(2*p+1, bB);
      U8 a0, a1;
      PACK8P(a0, s0, xep[0]); PACK8P(a1, s1, xep[1]);
      #pragma unroll
      for (int t = 0; t < 6; t++){
        accS[0][t] = mfma16(a0.v, bA[t], accS[0][t]);
        accS[1][t] = mfma16(a1.v, bA[t], accS[1][t]);
      }
    }
    {                                        // odd chunk 2p+1 from bB
      int nextc = (i < 15) ? 2*pn : (32 + off8);   // next pair even | first VV
      LD(nextc, bA);
      U8 a0, a1;
      PACK8P(a0, s0, xop[0]); PACK8P(a1, s1, xop[1]);
      #pragma unroll
      for (int t = 0; t < 6; t++){
        accS[0][t] = mfma16(a0.v, bB[t], accS[0][t]);
        accS[1][t] = mfma16(a1.v, bB[t], accS[1][t]);
      }
    }
  }
  // ===== VV: 8 chunks rotated by off8 =====
  #define VVA(uV, s, aa) { \
    int rr = (s) ? r1 : r0; \
    float c0 = b2f(X1V(rr, (uV)*3+0)); \
    float c1 = b2f(X1V(rr, (uV)*3+1)); \
    float c2 = b2f(X1V(rr, (uV)*3+2)); \
    _Pragma("unroll") \
    for (int q = 0; q < 4; q++){ \
      float lo = c0*ulo(y0p[s][q]) + c1*ulo(y1p[s][q]) + c2*ulo(y2p[s][q]); \
      float hi = c0*uhi(y0p[s][q]) + c1*uhi(y1p[s][q]) + c2*uhi(y2p[s][q]); \
      aa.u[q] = f2b2(lo, hi); \
    } }
  #pragma unroll 1
  for (int j = 0; j < 8; j += 2){
    int k0 = (j + off8) & 7;
    int k1 = (j + 1 + off8) & 7;
    int k2 = (j + 2 + off8) & 7;
    {                                        // chunk 32+k0 from bA
      LD(32+k1, bB);
      int u = (wv<<3) + k0;
      U8 a0, a1; VVA(u, 0, a0); VVA(u, 1, a1);
      #pragma unroll
      for (int t = 0; t < 6; t++){
        accS[0][t] = mfma16(a0.v, bA[t], accS[0][t]);
        accS[1][t] = mfma16(a1.v, bA[t], accS[1][t]);
      }
    }
    {                                        // chunk 32+k1 from bB
      int nextc = (j < 6) ? (32 + k2) : (40 + off6);   // next VV | first SV
      LD(nextc, bA);
      int u = (wv<<3) + k1;
      U8 a0, a1; VVA(u, 0, a0); VVA(u, 1, a1);
      #pragma unroll
      for (int t = 0; t < 6; t++){
        accS[0][t] = mfma16(a0.v, bB[t], accS[0][t]);
        accS[1][t] = mfma16(a1.v, bB[t], accS[1][t]);
      }
    }
  }
  // ===== SV: 6 chunks rotated by off6; body index = chunk index (runtime) =====
  #define SVBODY(chv, buf) { \
    _Pragma("unroll") \
    for (int uu = 0; uu < 3; uu++){ \
      int ui = (chv)*3 + uu; \
      if (ui < 16){ \
        int u = (wv<<4) + ui; \
        float s0 = b2f(X1S(r0, u)); \
        float s1 = b2f(X1S(r1, u)); \
        U8 a[2][3]; \
        PACK8P(a[0][0], s0, y0p[0]); PACK8P(a[0][1], s0, y1p[0]); PACK8P(a[0][2], s0, y2p[0]); \
        PACK8P(a[1][0], s1, y0p[1]); PACK8P(a[1][1], s1, y1p[1]); PACK8P(a[1][2], s1, y2p[1]); \
        _Pragma("unroll") \
        for (int t = 0; t < 2; t++){ \
          short8 b8 = buf[uu*2 + t]; \
          _Pragma("unroll") \
          for (int s = 0; s < 2; s++) \
            _Pragma("unroll") \
            for (int i2 = 0; i2 < 3; i2++) \
              accV[s][i2][t] = mfma16(a[s][i2].v, b8, accV[s][i2][t]); \
        } \
      } \
    } }
  #pragma unroll 1
  for (int j = 0; j < 6; j += 2){
    int c0i = j + off6;     if (c0i >= 6) c0i -= 6;
    int c1i = j + 1 + off6; if (c1i >= 6) c1i -= 6;
    int c2i = j + 2 + off6; if (c2i >= 6) c2i -= 6;
    { LD(40 + c1i, bB); SVBODY(c0i, bA); }
    {
      int nextc = (j < 4) ? (40 + c2i) : (46 + off6);  // next SV | first VS
      LD(nextc, bA);
      SVBODY(c1i, bB);
    }
  }
  // ===== VS: 6 chunks rotated by off6; phase p = pcv/3 (runtime) =====
  #define VSBODY(pcv, buf) { \
    const int p_ = (pcv)/3, ch_ = (pcv) - p_*3; \
    _Pragma("unroll") \
    for (int uu = 0; uu < 3; uu++){ \
      int ui = ch_*3 + uu; \
      if (ui < 8){ \
        int u = (wv<<3) + ui; \
        U8 a[2][3]; \
        _Pragma("unroll") \
        for (int s = 0; s < 2; s++){ \
          int rr = s ? r1 : r0; \
          float c0 = b2f(X1V(rr, u*3+0)); \
          float c1 = b2f(X1V(rr, u*3+1)); \
          float c2 = b2f(X1V(rr, u*3+2)); \
          const unsigned* xx = p_ ? xop[s] : xep[s]; \
          PACK8P(a[s][0], c0, xx); PACK8P(a[s][1], c1, xx); PACK8P(a[s][2], c2, xx); \
        } \
        _Pragma("unroll") \
        for (int t = 0; t < 2; t++){ \
          short8 b8 = buf[uu*2 + t]; \
          _Pragma("unroll") \
          for (int s = 0; s < 2; s++) \
            _Pragma("unroll") \
            for (int i2 = 0; i2 < 3; i2++) \
              accV[s][i2][t] = mfma16(a[s][i2].v, b8, accV[s][i2][t]); \
        } \
      } \
    } }
  #pragma unroll 1
  for (int j = 0; j < 6; j += 2){
    int c0i = j + off6;     if (c0i >= 6) c0i -= 6;
    int c1i = j + 1 + off6; if (c1i >= 6) c1i -= 6;
    int c2i = j + 2 + off6; if (c2i >= 6) c2i -= 6;
    { LD(46 + c1i, bB); VSBODY(c0i, bA); }
    {
      if (j < 4) LD(46 + c2i, bA);
      VSBODY(c1i, bB);
    }
  }

  // ---- gather partials: T0 = sub0's 12 tiles, T1 = sub1's ----
  f32x4 T0[12], T1[12];
  #pragma unroll
  for (int t = 0; t < 6; t++){ T0[t] = accS[0][t]; T1[t] = accS[1][t]; }
  #pragma unroll
  for (int t = 0; t < 2; t++)
    #pragma unroll
    for (int i = 0; i < 3; i++){
      T0[6+3*t+i] = accV[0][i][t]; T1[6+3*t+i] = accV[1][i][t];
    }

  // ---- cross-wave K-reduction through redf (A=slots0-11, B=12-23) ----
  #define PUT12(base, T) { _Pragma("unroll") for (int j=0;j<12;j++) \
    *(f32x4*)(redf + ((base)+j)*320 + ln*20 + (quad<<2)) = T[j]; }
  #define ADD12(base, T) { _Pragma("unroll") for (int j=0;j<12;j++) \
    T[j] += *(const f32x4*)(redf + ((base)+j)*320 + ln*20 + (quad<<2)); }

  __syncthreads();
  if (wv==1) PUT12(0, T0);  if (wv==2) PUT12(12, T1);
  __syncthreads();
  if (wv==0) ADD12(0, T0);  if (wv==3) ADD12(12, T1);
  __syncthreads();
  if (wv==2) PUT12(0, T0);  if (wv==1) PUT12(12, T1);
  __syncthreads();
  if (wv==0) ADD12(0, T0);  if (wv==3) ADD12(12, T1);
  __syncthreads();
  if (wv==3) PUT12(0, T0);  if (wv==0) PUT12(12, T1);
  __syncthreads();
  if (wv==0) ADD12(0, T0);  if (wv==3) ADD12(12, T1);
  // w0 now owns final sub0 tiles in T0; w3 owns final sub1 in T1.

  if (wv == 1 || wv == 2) return;
  const int s = (wv == 0) ? 0 : 1;
  f32x4* P = (wv == 0) ? T0 : T1;

  // ---- FC chain (owner wave, wave-private h buffer aliased on x1 region) ----
  f32x4 accF[4] = {z4,z4,z4,z4};
  {
    const float* fwp = few + (size_t)(ebase + s*16 + ln)*128;
    const short8* B = (const short8*)(wsb + FC1_OFF);
    #pragma unroll
    for (int c = 0; c < 4; c++){
      float4 fa  = *(const float4*)(fwp + c*32 + q8);
      float4 fbv = *(const float4*)(fwp + c*32 + q8 + 4);
      U8 a;
      a.u[0]=f2b2(fa.x,fa.y);   a.u[1]=f2b2(fa.z,fa.w);
      a.u[2]=f2b2(fbv.x,fbv.y); a.u[3]=f2b2(fbv.z,fbv.w);
      #pragma unroll
      for (int t = 0; t < 4; t++) accF[t] = mfma16(a.v, B[(c*4+t)*64 + lane], accF[t]);
    }
  }
  #pragma unroll
  for (int t = 0; t < 4; t++){
    float bb = fb1[(t<<4)+ln];
    #pragma unroll
    for (int r = 0; r < 4; r++)
      HB(wv, (quad<<2)+r, (t<<4)+ln) = f2b(silu_f(accF[t][r] + bb));
  }
  f32x4 acc2[4] = {z4,z4,z4,z4};
  {
    const short8* B = (const short8*)(wsb + FC2_OFF);
    #pragma unroll
    for (int c = 0; c < 2; c++){
      uint4 hq = *(const uint4*)&HB(wv, ln, c*32 + q8);
      U8 a; a.u[0]=hq.x; a.u[1]=hq.y; a.u[2]=hq.z; a.u[3]=hq.w;
      #pragma unroll
      for (int t = 0; t < 4; t++) acc2[t] = mfma16(a.v, B[(c*4+t)*64 + lane], acc2[t]);
    }
  }
  #pragma unroll
  for (int t = 0; t < 4; t++){
    float bb = fb2[(t<<4)+ln];
    #pragma unroll
    for (int r = 0; r < 4; r++)
      HB(wv, (quad<<2)+r, (t<<4)+ln) = f2b(silu_f(acc2[t][r] + bb));
  }
  f32x4 acc3[6] = {z4,z4,z4,z4,z4,z4};
  {
    const short8* B = (const short8*)(wsb + FC3_OFF);
    #pragma unroll
    for (int c = 0; c < 2; c++){
      uint4 hq = *(const uint4*)&HB(wv, ln, c*32 + q8);
      U8 a; a.u[0]=hq.x; a.u[1]=hq.y; a.u[2]=hq.z; a.u[3]=hq.w;
      #pragma unroll
      for (int t = 0; t < 6; t++) acc3[t] = mfma16(a.v, B[(c*6+t)*64 + lane], acc3[t]);
    }
  }

  // ---- epilogue (C-layout row = quad*4+r; 625*32 = 20000, no guards) ----
  #pragma unroll
  for (int r = 0; r < 4; r++){
    int eg = ebase + s*16 + (quad<<2) + r;
    float* op = out + (size_t)eg*160;
    #pragma unroll
    for (int t = 0; t < 4; t++)
      op[(t<<4)+ln] = silu_f(P[t][r]) * (acc3[t][r] + fb3[(t<<4)+ln]);
    #pragma unroll
    for (int tp = 0; tp < 2; tp++){
      int wc = (tp<<4) + ln;
      float f = sigm_f(P[4+tp][r]) * (acc3[4+tp][r] + fb3[64+wc]);
      op[64 + wc*3 + 0] = P[6+3*tp+0][r] * f;
      op[64 + wc*3 + 1] = P[6+3*tp+1][r] * f;
      op[64 + wc*3 + 2] = P[6+3*tp+2][r] * f;
    }
  }
}

extern "C" void kernel_launch(void* const* d_in, const int* in_sizes, int n_in,
                              void* d_out, int out_size, void* d_ws, size_t ws_size,
                              hipStream_t stream) {
  (void)in_sizes; (void)n_in; (void)out_size; (void)ws_size;
  unsigned short* wsb = (unsigned short*)d_ws;

  prep_weights<<<(WS_USH/8 + 255)/256, 256, 0, stream>>>(
      (const float*)d_in[3], (const float*)d_in[5],     // ss_s, ss_g
      (const float*)d_in[4], (const float*)d_in[6],     // vv_s, vv_g
      (const float*)d_in[7], (const float*)d_in[8],     // sv, vs
      (const float*)d_in[9], (const float*)d_in[11], (const float*)d_in[13],
      wsb);

  equiconv_main<<<E_TOT/32, 256, 0, stream>>>(
      (const float*)d_in[0], (const float*)d_in[1], (const float*)d_in[2],
      (const float*)d_in[10], (const float*)d_in[12], (const float*)d_in[14],
      (const unsigned short*)wsb, (float*)d_out);
}